// Round 18
// baseline (86.315 us; speedup 1.0000x reference)
//
#include <hip/hip_runtime.h>

#define NB   8
#define ND   64
#define NP   1024
#define KDIM 128
#define HID  256
#define OUTD 256
#define CSC  2.885390081777927f   // 2*log2(e)
#define PSTR 1048                 // sred plane stride: !=0 mod 32

typedef __attribute__((ext_vector_type(8))) short  bf16x8;
typedef __attribute__((ext_vector_type(4))) float  f32x4;

// E-trick: sigma = rcp(fma(Ed,Ep,1)); tanh = 1-2*sigma. EhpT transposed.
// R18: R17's register prefetch was sunk by the compiler (VGPR stayed 36);
// VALU/L1/LDS pipes serialized -> 43us. Fix: global_load_lds DMA staging
// (no VGPR path, can't be sunk), double-buffered 32KB chunks, barrier per
// chunk gives loads a ~770cy window. hrow+w2s merged to one b128 broadcast.

__device__ __forceinline__ ushort f2bf(float f) {
    unsigned u = __float_as_uint(f);
    return (ushort)((u + 0x7FFFu + ((u >> 16) & 1u)) >> 16);
}

#define GLD16(g, l) __builtin_amdgcn_global_load_lds(                        \
    (const __attribute__((address_space(1))) void*)(g),                      \
    (__attribute__((address_space(3))) void*)(l), 16, 0, 0)

// K0: cast X -> bf16 (k-contig); W -> bf16 TRANSPOSED (WT[n][k]).
__global__ __launch_bounds__(256) void k_cast(
    const float* __restrict__ Xd, const float* __restrict__ Xp,
    const float* __restrict__ Wd, const float* __restrict__ Wa,
    const float* __restrict__ Wp, const float* __restrict__ Wb,
    ushort* __restrict__ Xdbf, ushort* __restrict__ Xpbf,
    ushort* __restrict__ WdT, ushort* __restrict__ WaT,
    ushort* __restrict__ WpT, ushort* __restrict__ WbT) {
    int blk = blockIdx.x, t = threadIdx.x;
    if (blk < 1024) {
        size_t i = ((size_t)blk << 10) + ((size_t)t << 2);
        float4 v = *(const float4*)(Xp + i);
        ushort4 o; o.x = f2bf(v.x); o.y = f2bf(v.y); o.z = f2bf(v.z); o.w = f2bf(v.w);
        *(ushort4*)(Xpbf + i) = o;
    } else if (blk < 1088) {
        size_t i = ((size_t)(blk - 1024) << 10) + ((size_t)t << 2);
        float4 v = *(const float4*)(Xd + i);
        ushort4 o; o.x = f2bf(v.x); o.y = f2bf(v.y); o.z = f2bf(v.z); o.w = f2bf(v.w);
        *(ushort4*)(Xdbf + i) = o;
    } else {
        int r = blk - 1088, mat = r >> 5;
        const float* W = (mat == 0) ? Wd : (mat == 1) ? Wa : (mat == 2) ? Wp : Wb;
        ushort* WT = (mat == 0) ? WdT : (mat == 1) ? WaT : (mat == 2) ? WpT : WbT;
        int o0 = ((r & 31) << 10) + (t << 2);
        int n = o0 >> 7, k0 = o0 & 127;
        ushort4 o;
        o.x = f2bf(W[(k0 + 0) * HID + n]);
        o.y = f2bf(W[(k0 + 1) * HID + n]);
        o.z = f2bf(W[(k0 + 2) * HID + n]);
        o.w = f2bf(W[(k0 + 3) * HID + n]);
        *(ushort4*)(WT + o0) = o;
    }
}

// K1: MFMA projection + fused exp2 (verified absmax 0.0625).
__global__ __launch_bounds__(256) void k_proj_mfma(
    const ushort* __restrict__ Xpbf, const ushort* __restrict__ Xdbf,
    const ushort* __restrict__ WdT, const ushort* __restrict__ WaT,
    const ushort* __restrict__ WpT, const ushort* __restrict__ WbT,
    float* __restrict__ Ehd, float* __restrict__ Efd,
    float* __restrict__ EhpT, float* __restrict__ Efp) {
    int blk = blockIdx.x, t = threadIdx.x;
    const ushort *A, *B;
    float* out; size_t obase; int ostride, am0, bn0;
    if (blk < 512) {
        int mt = blk >> 2, nt = blk & 3;
        A = Xpbf; am0 = mt * 64; B = WbT; bn0 = nt * 64;
        out = Efp; obase = (size_t)am0 * HID + bn0; ostride = HID;
    } else if (blk < 1024) {
        int r = blk - 512, b = r >> 6, rr = r & 63;
        int mt = rr >> 4, nt = rr & 15;
        A = WpT; am0 = mt * 64;
        B = Xpbf + (size_t)b * NP * KDIM; bn0 = nt * 64;
        out = EhpT; obase = ((size_t)(b * 256 + am0)) * NP + bn0; ostride = NP;
    } else if (blk < 1056) {
        int r = blk - 1024; int mt = r >> 2, nt = r & 3;
        A = Xdbf; am0 = mt * 64; B = WdT; bn0 = nt * 64;
        out = Ehd; obase = (size_t)am0 * HID + bn0; ostride = HID;
    } else {
        int r = blk - 1056; int mt = r >> 2, nt = r & 3;
        A = Xdbf; am0 = mt * 64; B = WaT; bn0 = nt * 64;
        out = Efd; obase = (size_t)am0 * HID + bn0; ostride = HID;
    }
    int l = t & 63, w = t >> 6;
    int wm = (w >> 1) << 5, wn = (w & 1) << 5;
    int lr = l & 15, lk = (l >> 4) << 3;
    const ushort* Ab = A + (size_t)(am0 + wm + lr) * KDIM + lk;
    const ushort* Bb = B + (size_t)(bn0 + wn + lr) * KDIM + lk;

    bf16x8 af[2][4], bfr[2][4];
#pragma unroll
    for (int f = 0; f < 2; ++f)
#pragma unroll
        for (int ks = 0; ks < 4; ++ks) {
            af[f][ks]  = *(const bf16x8*)(Ab + (size_t)(f << 4) * KDIM + (ks << 5));
            bfr[f][ks] = *(const bf16x8*)(Bb + (size_t)(f << 4) * KDIM + (ks << 5));
        }

    f32x4 acc[2][2];
#pragma unroll
    for (int mf = 0; mf < 2; ++mf)
#pragma unroll
        for (int nf = 0; nf < 2; ++nf) acc[mf][nf] = (f32x4){0.f, 0.f, 0.f, 0.f};
#pragma unroll
    for (int ks = 0; ks < 4; ++ks)
#pragma unroll
        for (int mf = 0; mf < 2; ++mf)
#pragma unroll
            for (int nf = 0; nf < 2; ++nf)
                acc[mf][nf] = __builtin_amdgcn_mfma_f32_16x16x32_bf16(
                    af[mf][ks], bfr[nf][ks], acc[mf][nf], 0, 0, 0);

#pragma unroll
    for (int mf = 0; mf < 2; ++mf)
#pragma unroll
        for (int nf = 0; nf < 2; ++nf)
#pragma unroll
            for (int r = 0; r < 4; ++r) {
                int m = wm + (mf << 4) + ((l >> 4) << 2) + r;
                int n = wn + (nf << 4) + (l & 15);
                out[obase + (size_t)m * ostride + n] =
                    __builtin_amdgcn_exp2f(acc[mf][nf][r] * CSC);
            }
}

// K2: FUSED scores+softmax+facc, 2 i-rows/block, grid 256, 1024 thr.
// Streaming phases read from double-buffered LDS filled by global_load_lds
// DMA: STAGE(c+1) issued before COMPUTE(c), one barrier per 32KB chunk.
__global__ __launch_bounds__(1024) void k_fused(
    const float* __restrict__ Ehd, const float* __restrict__ EhpT,
    const float* __restrict__ Efd, const float* __restrict__ Efp,
    const float* __restrict__ wsc, float* __restrict__ part) {
    int blk = blockIdx.x;
    int b = blk & 7, pair = blk >> 3;
    int row0 = b * ND + pair * 2;
    int t = threadIdx.x;

    __shared__ float  ebuf[2][8192];     // 64 KB double buffer
    __shared__ float4 hw4[256];          // (Ehd r0, Ehd r1, -2w, 0)  4 KB
    __shared__ float2 a2[1024];          // 8 KB
    __shared__ float  sred[8 * PSTR];    // 33.5 KB
    __shared__ float  wsum0[16], wsum1[16];

    if (t < 256)
        hw4[t] = make_float4(Ehd[((size_t)row0 << 8) + t],
                             Ehd[((size_t)(row0 + 1) << 8) + t],
                             -2.0f * wsc[t], 0.f);

    const float* Eb = EhpT + ((size_t)(b << 8)) * NP;   // [256][1024]
    const float* Fb = Efp + ((size_t)(b * NP)) * 256;   // [1024][256]

#define STAGE(dst, gbase)                                                    \
    do {                                                                     \
        GLD16((gbase) + (t << 2),        &ebuf[dst][(t << 2)]);              \
        GLD16((gbase) + 4096 + (t << 2), &ebuf[dst][4096 + (t << 2)]);       \
    } while (0)

    // ================= phase 1: scores =================
    STAGE(0, Eb);
    __syncthreads();                     // hw4 + chunk 0 ready

    float a00 = 0, a01 = 0, a02 = 0, a03 = 0;
    float a10 = 0, a11 = 0, a12 = 0, a13 = 0;
    int jq = t & 255, rep = t >> 8;
    for (int c = 0; c < 32; ++c) {
        if (c < 31) STAGE((c + 1) & 1, Eb + ((size_t)(c + 1) << 13));
        const float* eb = ebuf[c & 1];
#pragma unroll
        for (int hl = 0; hl < 2; ++hl) {
            int hloc = rep + (hl << 2);
            float4 hw = hw4[(c << 3) + hloc];    // broadcast b128
            float4 p = *(const float4*)(eb + (hloc << 10) + (jq << 2));
            a00 = fmaf(hw.z, __builtin_amdgcn_rcpf(fmaf(hw.x, p.x, 1.f)), a00);
            a01 = fmaf(hw.z, __builtin_amdgcn_rcpf(fmaf(hw.x, p.y, 1.f)), a01);
            a02 = fmaf(hw.z, __builtin_amdgcn_rcpf(fmaf(hw.x, p.z, 1.f)), a02);
            a03 = fmaf(hw.z, __builtin_amdgcn_rcpf(fmaf(hw.x, p.w, 1.f)), a03);
            a10 = fmaf(hw.z, __builtin_amdgcn_rcpf(fmaf(hw.y, p.x, 1.f)), a10);
            a11 = fmaf(hw.z, __builtin_amdgcn_rcpf(fmaf(hw.y, p.y, 1.f)), a11);
            a12 = fmaf(hw.z, __builtin_amdgcn_rcpf(fmaf(hw.y, p.z, 1.f)), a12);
            a13 = fmaf(hw.z, __builtin_amdgcn_rcpf(fmaf(hw.y, p.w, 1.f)), a13);
        }
        __syncthreads();                 // chunk c+1 landed; buf[c-1] free
    }
    {
        int base = (rep << 8) + jq;      // == t
        sred[0 * PSTR + base] = a00;  sred[1 * PSTR + base] = a01;
        sred[2 * PSTR + base] = a02;  sred[3 * PSTR + base] = a03;
        sred[4 * PSTR + base] = a10;  sred[5 * PSTR + base] = a11;
        sred[6 * PSTR + base] = a12;  sred[7 * PSTR + base] = a13;
    }
    STAGE(0, Fb);                        // phase-3 chunk 0, lands under phase 2
    __syncthreads();

    // ================= phase 2: softmax =================
    {
        int jq2 = t >> 2, c = t & 3;
        const float* p0 = sred + c * PSTR + jq2;
        const float* p1 = sred + (4 + c) * PSTR + jq2;
        float sc0 = (p0[0] + p0[256]) + (p0[512] + p0[768]);
        float sc1 = (p1[0] + p1[256]) + (p1[512] + p1[768]);
        const float L2E = 1.4426950408889634f;
        float e0 = __builtin_amdgcn_exp2f(sc0 * L2E);
        float e1 = __builtin_amdgcn_exp2f(sc1 * L2E);
        float s0 = e0, s1 = e1;
#pragma unroll
        for (int off = 32; off > 0; off >>= 1) {
            s0 += __shfl_xor(s0, off, 64);
            s1 += __shfl_xor(s1, off, 64);
        }
        if ((t & 63) == 0) { wsum0[t >> 6] = s0; wsum1[t >> 6] = s1; }
        __syncthreads();
        float tot0 = 0.f, tot1 = 0.f;
#pragma unroll
        for (int w = 0; w < 16; ++w) { tot0 += wsum0[w]; tot1 += wsum1[w]; }
        float sn0 = -2.0f * __builtin_amdgcn_rcpf(tot0);
        float sn1 = -2.0f * __builtin_amdgcn_rcpf(tot1);
        a2[t] = make_float2(e0 * sn0, e1 * sn1);
    }
    __syncthreads();                     // a2 ready

    // ================= phase 3: facc =================
    float b00 = 0, b01 = 0, b02 = 0, b03 = 0;
    float b10 = 0, b11 = 0, b12 = 0, b13 = 0;
    int oq = t & 63, wv = t >> 6;        // wv = wave index 0..15
    int o0 = oq << 2;
    float4 fd0 = *(const float4*)(Efd + ((size_t)row0 << 8) + o0);
    float4 fd1 = *(const float4*)(Efd + ((size_t)(row0 + 1) << 8) + o0);
    for (int c = 0; c < 32; ++c) {
        if (c < 31) STAGE((c + 1) & 1, Fb + ((size_t)(c + 1) << 13));
        const float* eb = ebuf[c & 1];
#pragma unroll
        for (int jl = 0; jl < 2; ++jl) {
            int jloc = wv + (jl << 4);
            float2 av = a2[(c << 5) + jloc];     // broadcast b64
            float4 f = *(const float4*)(eb + (jloc << 8) + o0);
            b00 = fmaf(av.x, __builtin_amdgcn_rcpf(fmaf(fd0.x, f.x, 1.f)), b00);
            b01 = fmaf(av.x, __builtin_amdgcn_rcpf(fmaf(fd0.y, f.y, 1.f)), b01);
            b02 = fmaf(av.x, __builtin_amdgcn_rcpf(fmaf(fd0.z, f.z, 1.f)), b02);
            b03 = fmaf(av.x, __builtin_amdgcn_rcpf(fmaf(fd0.w, f.w, 1.f)), b03);
            b10 = fmaf(av.y, __builtin_amdgcn_rcpf(fmaf(fd1.x, f.x, 1.f)), b10);
            b11 = fmaf(av.y, __builtin_amdgcn_rcpf(fmaf(fd1.y, f.y, 1.f)), b11);
            b12 = fmaf(av.y, __builtin_amdgcn_rcpf(fmaf(fd1.z, f.z, 1.f)), b12);
            b13 = fmaf(av.y, __builtin_amdgcn_rcpf(fmaf(fd1.w, f.w, 1.f)), b13);
        }
        __syncthreads();
    }
    {
        int base = (wv << 6) + oq;       // == t
        sred[0 * PSTR + base] = b00;  sred[1 * PSTR + base] = b01;
        sred[2 * PSTR + base] = b02;  sred[3 * PSTR + base] = b03;
        sred[4 * PSTR + base] = b10;  sred[5 * PSTR + base] = b11;
        sred[6 * PSTR + base] = b12;  sred[7 * PSTR + base] = b13;
    }
    __syncthreads();

    if (t < 512) {
        int r = t >> 8, o = t & 255;
        int oq2 = o >> 2, c2 = o & 3;
        const float* pk = sred + (r * 4 + c2) * PSTR + oq2;
        float s = 0.f;
#pragma unroll
        for (int g = 0; g < 16; ++g) s += pk[g << 6];
        part[((size_t)((b << 6) + (pair << 1) + r) << 8) + o] = s;
    }
#undef STAGE
}

// K3: out[b][o] = 64 + sum over 64 i-rows. grid = 8. part layout [b][i][o].
__global__ __launch_bounds__(256) void k_reduce(
    const float* __restrict__ part, float* __restrict__ out) {
    int b = blockIdx.x, t = threadIdx.x;
    float s = 64.0f;
#pragma unroll 8
    for (int i = 0; i < 64; ++i)
        s += part[((size_t)((b << 6) + i) << 8) + t];
    out[(b << 8) + t] = s;
}

extern "C" void kernel_launch(void* const* d_in, const int* in_sizes, int n_in,
                              void* d_out, int out_size, void* d_ws, size_t ws_size,
                              hipStream_t stream) {
    const float* Xd  = (const float*)d_in[0];
    const float* Xp  = (const float*)d_in[1];
    const float* Wd  = (const float*)d_in[2];
    const float* Wp  = (const float*)d_in[3];
    const float* Wa  = (const float*)d_in[4];
    const float* Wb  = (const float*)d_in[5];
    const float* wsc = (const float*)d_in[6];
    float* out = (float*)d_out;

    float* ws = (float*)d_ws;
    float* Ehd  = ws;
    float* Efd  = Ehd + NB * ND * HID;
    float* EhpT = Efd + NB * ND * OUTD;
    float* Efp  = EhpT + NB * NP * HID;
    float* stage = Efp + NB * NP * OUTD;
    ushort* Xpbf = (ushort*)stage;
    ushort* Xdbf = Xpbf + NB * NP * KDIM;
    ushort* WdT  = Xdbf + 65536;
    ushort* WaT  = WdT + 32768;
    ushort* WpT  = WaT + 32768;
    ushort* WbT  = WpT + 32768;
    float* part  = stage;

    k_cast     <<<1216, 256, 0, stream>>>(Xd, Xp, Wd, Wa, Wp, Wb,
                                          Xdbf, Xpbf, WdT, WaT, WpT, WbT);
    k_proj_mfma<<<1088, 256, 0, stream>>>(Xpbf, Xdbf, WdT, WaT, WpT, WbT,
                                          Ehd, Efd, EhpT, Efp);
    k_fused    <<<256, 1024, 0, stream>>>(Ehd, EhpT, Efd, Efp, wsc, part);
    k_reduce   <<<NB, 256, 0, stream>>>(part, out);
}

// Round 19
// 62.686 us; speedup vs baseline: 1.3769x; 1.3769x over previous
//
#include <hip/hip_runtime.h>

#define NB   8
#define ND   64
#define NP   1024
#define KDIM 128
#define HID  256
#define OUTD 256
#define CSC  2.885390081777927f   // 2*log2(e)
#define PSTR 1048                 // sred plane stride: !=0 mod 32

typedef __attribute__((ext_vector_type(8))) short  bf16x8;
typedef __attribute__((ext_vector_type(4))) float  f32x4;

// E-trick: sigma = rcp(fma(Ed,Ep,1)); tanh = 1-2*sigma. EhpT transposed.
// R19: revert R18's DMA staging (barrier drained vmcnt 64x -> barrier-bound).
// R17 base + __launch_bounds__(1024,4): declares the true 1-block/CU
// occupancy -> 128-VGPR budget, so the 4-wide rotating prefetch groups in
// phases 1/3 are not sunk to point-of-use (R10/R17 failure mode).

__device__ __forceinline__ ushort f2bf(float f) {
    unsigned u = __float_as_uint(f);
    return (ushort)((u + 0x7FFFu + ((u >> 16) & 1u)) >> 16);
}

// K0: cast X -> bf16 (k-contig); W -> bf16 TRANSPOSED (WT[n][k]).
__global__ __launch_bounds__(256) void k_cast(
    const float* __restrict__ Xd, const float* __restrict__ Xp,
    const float* __restrict__ Wd, const float* __restrict__ Wa,
    const float* __restrict__ Wp, const float* __restrict__ Wb,
    ushort* __restrict__ Xdbf, ushort* __restrict__ Xpbf,
    ushort* __restrict__ WdT, ushort* __restrict__ WaT,
    ushort* __restrict__ WpT, ushort* __restrict__ WbT) {
    int blk = blockIdx.x, t = threadIdx.x;
    if (blk < 1024) {
        size_t i = ((size_t)blk << 10) + ((size_t)t << 2);
        float4 v = *(const float4*)(Xp + i);
        ushort4 o; o.x = f2bf(v.x); o.y = f2bf(v.y); o.z = f2bf(v.z); o.w = f2bf(v.w);
        *(ushort4*)(Xpbf + i) = o;
    } else if (blk < 1088) {
        size_t i = ((size_t)(blk - 1024) << 10) + ((size_t)t << 2);
        float4 v = *(const float4*)(Xd + i);
        ushort4 o; o.x = f2bf(v.x); o.y = f2bf(v.y); o.z = f2bf(v.z); o.w = f2bf(v.w);
        *(ushort4*)(Xdbf + i) = o;
    } else {
        int r = blk - 1088, mat = r >> 5;
        const float* W = (mat == 0) ? Wd : (mat == 1) ? Wa : (mat == 2) ? Wp : Wb;
        ushort* WT = (mat == 0) ? WdT : (mat == 1) ? WaT : (mat == 2) ? WpT : WbT;
        int o0 = ((r & 31) << 10) + (t << 2);
        int n = o0 >> 7, k0 = o0 & 127;
        ushort4 o;
        o.x = f2bf(W[(k0 + 0) * HID + n]);
        o.y = f2bf(W[(k0 + 1) * HID + n]);
        o.z = f2bf(W[(k0 + 2) * HID + n]);
        o.w = f2bf(W[(k0 + 3) * HID + n]);
        *(ushort4*)(WT + o0) = o;
    }
}

// K1: MFMA projection + fused exp2 (verified absmax 0.0625).
__global__ __launch_bounds__(256) void k_proj_mfma(
    const ushort* __restrict__ Xpbf, const ushort* __restrict__ Xdbf,
    const ushort* __restrict__ WdT, const ushort* __restrict__ WaT,
    const ushort* __restrict__ WpT, const ushort* __restrict__ WbT,
    float* __restrict__ Ehd, float* __restrict__ Efd,
    float* __restrict__ EhpT, float* __restrict__ Efp) {
    int blk = blockIdx.x, t = threadIdx.x;
    const ushort *A, *B;
    float* out; size_t obase; int ostride, am0, bn0;
    if (blk < 512) {
        int mt = blk >> 2, nt = blk & 3;
        A = Xpbf; am0 = mt * 64; B = WbT; bn0 = nt * 64;
        out = Efp; obase = (size_t)am0 * HID + bn0; ostride = HID;
    } else if (blk < 1024) {
        int r = blk - 512, b = r >> 6, rr = r & 63;
        int mt = rr >> 4, nt = rr & 15;
        A = WpT; am0 = mt * 64;
        B = Xpbf + (size_t)b * NP * KDIM; bn0 = nt * 64;
        out = EhpT; obase = ((size_t)(b * 256 + am0)) * NP + bn0; ostride = NP;
    } else if (blk < 1056) {
        int r = blk - 1024; int mt = r >> 2, nt = r & 3;
        A = Xdbf; am0 = mt * 64; B = WdT; bn0 = nt * 64;
        out = Ehd; obase = (size_t)am0 * HID + bn0; ostride = HID;
    } else {
        int r = blk - 1056; int mt = r >> 2, nt = r & 3;
        A = Xdbf; am0 = mt * 64; B = WaT; bn0 = nt * 64;
        out = Efd; obase = (size_t)am0 * HID + bn0; ostride = HID;
    }
    int l = t & 63, w = t >> 6;
    int wm = (w >> 1) << 5, wn = (w & 1) << 5;
    int lr = l & 15, lk = (l >> 4) << 3;
    const ushort* Ab = A + (size_t)(am0 + wm + lr) * KDIM + lk;
    const ushort* Bb = B + (size_t)(bn0 + wn + lr) * KDIM + lk;

    bf16x8 af[2][4], bfr[2][4];
#pragma unroll
    for (int f = 0; f < 2; ++f)
#pragma unroll
        for (int ks = 0; ks < 4; ++ks) {
            af[f][ks]  = *(const bf16x8*)(Ab + (size_t)(f << 4) * KDIM + (ks << 5));
            bfr[f][ks] = *(const bf16x8*)(Bb + (size_t)(f << 4) * KDIM + (ks << 5));
        }

    f32x4 acc[2][2];
#pragma unroll
    for (int mf = 0; mf < 2; ++mf)
#pragma unroll
        for (int nf = 0; nf < 2; ++nf) acc[mf][nf] = (f32x4){0.f, 0.f, 0.f, 0.f};
#pragma unroll
    for (int ks = 0; ks < 4; ++ks)
#pragma unroll
        for (int mf = 0; mf < 2; ++mf)
#pragma unroll
            for (int nf = 0; nf < 2; ++nf)
                acc[mf][nf] = __builtin_amdgcn_mfma_f32_16x16x32_bf16(
                    af[mf][ks], bfr[nf][ks], acc[mf][nf], 0, 0, 0);

#pragma unroll
    for (int mf = 0; mf < 2; ++mf)
#pragma unroll
        for (int nf = 0; nf < 2; ++nf)
#pragma unroll
            for (int r = 0; r < 4; ++r) {
                int m = wm + (mf << 4) + ((l >> 4) << 2) + r;
                int n = wn + (nf << 4) + (l & 15);
                out[obase + (size_t)m * ostride + n] =
                    __builtin_amdgcn_exp2f(acc[mf][nf][r] * CSC);
            }
}

// K2: FUSED scores+softmax+facc, 2 i-rows/block, grid 256, 1024 thr.
// launch_bounds(1024,4) -> 128-VGPR budget -> 4-wide rotating prefetch
// groups survive scheduling (R10/R17: sunk at default budget).
__global__ __launch_bounds__(1024, 4) void k_fused(
    const float* __restrict__ Ehd, const float* __restrict__ EhpT,
    const float* __restrict__ Efd, const float* __restrict__ Efp,
    const float* __restrict__ wsc, float* __restrict__ part) {
    int blk = blockIdx.x;
    int b = blk & 7, pair = blk >> 3;
    int row0 = b * ND + pair * 2;
    int t = threadIdx.x;

    __shared__ float2 hrow[256];
    __shared__ float  w2s[256];
    __shared__ float2 a2[1024];
    __shared__ float  sred[8 * PSTR];
    __shared__ float  wsum0[16], wsum1[16];

    if (t < 256) {
        hrow[t] = make_float2(Ehd[((size_t)row0 << 8) + t],
                              Ehd[((size_t)(row0 + 1) << 8) + t]);
        w2s[t] = -2.0f * wsc[t];
    }
    __syncthreads();

    // ---- phase 1: 16 groups of 4 h-rows, 1-group-ahead prefetch ----
    {
        int jq = t & 255, hq = t >> 8;
        const float* pB = EhpT + ((size_t)((b << 8) + (hq << 6))) * NP + (jq << 2);
        float a00 = 0, a01 = 0, a02 = 0, a03 = 0;
        float a10 = 0, a11 = 0, a12 = 0, a13 = 0;
        float4 c0 = *(const float4*)(pB);
        float4 c1 = *(const float4*)(pB + NP);
        float4 c2 = *(const float4*)(pB + 2 * (size_t)NP);
        float4 c3 = *(const float4*)(pB + 3 * (size_t)NP);

#define SEVAL(pv, hh)                                                         \
        do {                                                                  \
            float2 hv = hrow[hh]; float wv = w2s[hh];                         \
            a00 = fmaf(wv, __builtin_amdgcn_rcpf(fmaf(hv.x, pv.x, 1.f)), a00);\
            a01 = fmaf(wv, __builtin_amdgcn_rcpf(fmaf(hv.x, pv.y, 1.f)), a01);\
            a02 = fmaf(wv, __builtin_amdgcn_rcpf(fmaf(hv.x, pv.z, 1.f)), a02);\
            a03 = fmaf(wv, __builtin_amdgcn_rcpf(fmaf(hv.x, pv.w, 1.f)), a03);\
            a10 = fmaf(wv, __builtin_amdgcn_rcpf(fmaf(hv.y, pv.x, 1.f)), a10);\
            a11 = fmaf(wv, __builtin_amdgcn_rcpf(fmaf(hv.y, pv.y, 1.f)), a11);\
            a12 = fmaf(wv, __builtin_amdgcn_rcpf(fmaf(hv.y, pv.z, 1.f)), a12);\
            a13 = fmaf(wv, __builtin_amdgcn_rcpf(fmaf(hv.y, pv.w, 1.f)), a13);\
        } while (0)

#pragma unroll
        for (int hg = 0; hg < 16; ++hg) {
            float4 n0, n1, n2, n3;
            if (hg < 15) {
                const float* pn = pB + ((size_t)((hg + 1) << 2)) * NP;
                n0 = *(const float4*)(pn);
                n1 = *(const float4*)(pn + NP);
                n2 = *(const float4*)(pn + 2 * (size_t)NP);
                n3 = *(const float4*)(pn + 3 * (size_t)NP);
            }
            int h = (hq << 6) + (hg << 2);
            SEVAL(c0, h + 0);
            SEVAL(c1, h + 1);
            SEVAL(c2, h + 2);
            SEVAL(c3, h + 3);
            c0 = n0; c1 = n1; c2 = n2; c3 = n3;
        }
#undef SEVAL
        int base = (hq << 8) + jq;
        sred[0 * PSTR + base] = a00;  sred[1 * PSTR + base] = a01;
        sred[2 * PSTR + base] = a02;  sred[3 * PSTR + base] = a03;
        sred[4 * PSTR + base] = a10;  sred[5 * PSTR + base] = a11;
        sred[6 * PSTR + base] = a12;  sred[7 * PSTR + base] = a13;
    }
    __syncthreads();

    // ---- phase 2: softmax ----
    {
        int jq2 = t >> 2, c = t & 3;
        const float* p0 = sred + c * PSTR + jq2;
        const float* p1 = sred + (4 + c) * PSTR + jq2;
        float sc0 = (p0[0] + p0[256]) + (p0[512] + p0[768]);
        float sc1 = (p1[0] + p1[256]) + (p1[512] + p1[768]);
        const float L2E = 1.4426950408889634f;
        float e0 = __builtin_amdgcn_exp2f(sc0 * L2E);
        float e1 = __builtin_amdgcn_exp2f(sc1 * L2E);
        float s0 = e0, s1 = e1;
#pragma unroll
        for (int off = 32; off > 0; off >>= 1) {
            s0 += __shfl_xor(s0, off, 64);
            s1 += __shfl_xor(s1, off, 64);
        }
        if ((t & 63) == 0) { wsum0[t >> 6] = s0; wsum1[t >> 6] = s1; }
        __syncthreads();
        float tot0 = 0.f, tot1 = 0.f;
#pragma unroll
        for (int w = 0; w < 16; ++w) { tot0 += wsum0[w]; tot1 += wsum1[w]; }
        float sn0 = -2.0f * __builtin_amdgcn_rcpf(tot0);
        float sn1 = -2.0f * __builtin_amdgcn_rcpf(tot1);
        a2[t] = make_float2(e0 * sn0, e1 * sn1);
    }
    __syncthreads();

    // ---- phase 3: 16 groups of 4 j-rows, 1-group-ahead prefetch ----
    {
        int oq = t & 63, jg = t >> 6;
        int o0 = oq << 2;
        float4 fd0 = *(const float4*)(Efd + ((size_t)row0 << 8) + o0);
        float4 fd1 = *(const float4*)(Efd + ((size_t)(row0 + 1) << 8) + o0);
        const float* fpB = Efp + ((size_t)(b * NP + (jg << 6)) << 8) + o0;
        float b00 = 0, b01 = 0, b02 = 0, b03 = 0;
        float b10 = 0, b11 = 0, b12 = 0, b13 = 0;
        float4 c0 = *(const float4*)(fpB);
        float4 c1 = *(const float4*)(fpB + 256);
        float4 c2 = *(const float4*)(fpB + 512);
        float4 c3 = *(const float4*)(fpB + 768);

#define FEVAL(fv, jj)                                                         \
        do {                                                                  \
            float2 av = a2[(jg << 6) + (jj)];                                 \
            b00 = fmaf(av.x, __builtin_amdgcn_rcpf(fmaf(fd0.x, fv.x, 1.f)), b00);\
            b01 = fmaf(av.x, __builtin_amdgcn_rcpf(fmaf(fd0.y, fv.y, 1.f)), b01);\
            b02 = fmaf(av.x, __builtin_amdgcn_rcpf(fmaf(fd0.z, fv.z, 1.f)), b02);\
            b03 = fmaf(av.x, __builtin_amdgcn_rcpf(fmaf(fd0.w, fv.w, 1.f)), b03);\
            b10 = fmaf(av.y, __builtin_amdgcn_rcpf(fmaf(fd1.x, fv.x, 1.f)), b10);\
            b11 = fmaf(av.y, __builtin_amdgcn_rcpf(fmaf(fd1.y, fv.y, 1.f)), b11);\
            b12 = fmaf(av.y, __builtin_amdgcn_rcpf(fmaf(fd1.z, fv.z, 1.f)), b12);\
            b13 = fmaf(av.y, __builtin_amdgcn_rcpf(fmaf(fd1.w, fv.w, 1.f)), b13);\
        } while (0)

#pragma unroll
        for (int jg4 = 0; jg4 < 16; ++jg4) {
            float4 n0, n1, n2, n3;
            if (jg4 < 15) {
                const float* pn = fpB + ((size_t)((jg4 + 1) << 2) << 8);
                n0 = *(const float4*)(pn);
                n1 = *(const float4*)(pn + 256);
                n2 = *(const float4*)(pn + 512);
                n3 = *(const float4*)(pn + 768);
            }
            int j = jg4 << 2;
            FEVAL(c0, j + 0);
            FEVAL(c1, j + 1);
            FEVAL(c2, j + 2);
            FEVAL(c3, j + 3);
            c0 = n0; c1 = n1; c2 = n2; c3 = n3;
        }
#undef FEVAL
        int base = (jg << 6) + oq;
        sred[0 * PSTR + base] = b00;  sred[1 * PSTR + base] = b01;
        sred[2 * PSTR + base] = b02;  sred[3 * PSTR + base] = b03;
        sred[4 * PSTR + base] = b10;  sred[5 * PSTR + base] = b11;
        sred[6 * PSTR + base] = b12;  sred[7 * PSTR + base] = b13;
    }
    __syncthreads();

    if (t < 512) {
        int r = t >> 8, o = t & 255;
        int oq2 = o >> 2, c2 = o & 3;
        const float* pk = sred + (r * 4 + c2) * PSTR + oq2;
        float s = 0.f;
#pragma unroll
        for (int g = 0; g < 16; ++g) s += pk[g << 6];
        part[((size_t)((b << 6) + (pair << 1) + r) << 8) + o] = s;
    }
}

// K3: out[b][o] = 64 + sum over 64 i-rows. grid = 8. part layout [b][i][o].
__global__ __launch_bounds__(256) void k_reduce(
    const float* __restrict__ part, float* __restrict__ out) {
    int b = blockIdx.x, t = threadIdx.x;
    float s = 64.0f;
#pragma unroll 8
    for (int i = 0; i < 64; ++i)
        s += part[((size_t)((b << 6) + i) << 8) + t];
    out[(b << 8) + t] = s;
}

extern "C" void kernel_launch(void* const* d_in, const int* in_sizes, int n_in,
                              void* d_out, int out_size, void* d_ws, size_t ws_size,
                              hipStream_t stream) {
    const float* Xd  = (const float*)d_in[0];
    const float* Xp  = (const float*)d_in[1];
    const float* Wd  = (const float*)d_in[2];
    const float* Wp  = (const float*)d_in[3];
    const float* Wa  = (const float*)d_in[4];
    const float* Wb  = (const float*)d_in[5];
    const float* wsc = (const float*)d_in[6];
    float* out = (float*)d_out;

    float* ws = (float*)d_ws;
    float* Ehd  = ws;
    float* Efd  = Ehd + NB * ND * HID;
    float* EhpT = Efd + NB * ND * OUTD;
    float* Efp  = EhpT + NB * NP * HID;
    float* stage = Efp + NB * NP * OUTD;
    ushort* Xpbf = (ushort*)stage;
    ushort* Xdbf = Xpbf + NB * NP * KDIM;
    ushort* WdT  = Xdbf + 65536;
    ushort* WaT  = WdT + 32768;
    ushort* WpT  = WaT + 32768;
    ushort* WbT  = WpT + 32768;
    float* part  = stage;

    k_cast     <<<1216, 256, 0, stream>>>(Xd, Xp, Wd, Wa, Wp, Wb,
                                          Xdbf, Xpbf, WdT, WaT, WpT, WbT);
    k_proj_mfma<<<1088, 256, 0, stream>>>(Xpbf, Xdbf, WdT, WaT, WpT, WbT,
                                          Ehd, Efd, EhpT, Efp);
    k_fused    <<<256, 1024, 0, stream>>>(Ehd, EhpT, Efd, Efp, wsc, part);
    k_reduce   <<<NB, 256, 0, stream>>>(part, out);
}